// Round 1
// baseline (42.052 us; speedup 1.0000x reference)
//
#include <hip/hip_runtime.h>
#include <hip/hip_bf16.h>
#include <math.h>

// Problem constants
#define BB 8
#define NN 1024
#define TT 512
#define KK 9
#define HH 32

#define NCHUNK 32          // n-chunks in reduction
#define NPER   (NN/NCHUNK) // 32 n per chunk
#define TTILE  256         // t per block

__constant__ float c_epos[KK][3] = {
    { 0.30f,  0.25f, 0.00f},
    {-0.30f,  0.25f, 0.00f},
    {-0.05f, -0.40f, 0.00f},
    { 0.03f,  0.05f, 0.20f},
    { 0.00f,  0.05f, 0.22f},
    {-0.04f,  0.01f, 0.21f},
    {-0.08f, -0.02f, 0.18f},
    {-0.14f, -0.02f, 0.13f},
    {-0.20f, -0.02f, 0.07f},
};

// Kernel 1: A[b,n,k] = amp * (dd . r_vec) * correction / (r2+0.04)^1.5
__global__ __launch_bounds__(256) void coef_kernel(
    const float* __restrict__ pos,   // (B,N,3)
    const float* __restrict__ dd,    // (B,N,3)
    const float* __restrict__ amp,   // (B,N)
    const float* __restrict__ eoff,  // (B,K,3)
    const float* __restrict__ W1,    // (H,7)
    const float* __restrict__ b1,    // (H)
    const float* __restrict__ W2,    // (1,H)
    const float* __restrict__ b2,    // (1)
    float* __restrict__ A)           // (B,N,K)
{
    __shared__ float sW1[HH * 7];
    __shared__ float sb1[HH];
    __shared__ float sW2[HH];
    const int tid = threadIdx.x;
    for (int i = tid; i < HH * 7; i += 256) sW1[i] = W1[i];
    if (tid < HH)                sb1[tid] = b1[tid];
    if (tid >= 64 && tid < 96)   sW2[tid - 64] = W2[tid - 64];
    __syncthreads();

    const int idx = blockIdx.x * 256 + tid;     // = bn*9 + k, total 73728
    if (idx >= BB * NN * KK) return;
    const int k  = idx % KK;
    const int bn = idx / KK;
    const int b  = bn / NN;

    const float px = pos[bn * 3 + 0];
    const float py = pos[bn * 3 + 1];
    const float pz = pos[bn * 3 + 2];

    const float ex = c_epos[k][0] + eoff[(b * KK + k) * 3 + 0];
    const float ey = c_epos[k][1] + eoff[(b * KK + k) * 3 + 1];
    const float ez = c_epos[k][2] + eoff[(b * KK + k) * 3 + 2];

    const float rx = ex - px, ry = ey - py, rz = ez - pz;
    const float r2 = rx * rx + ry * ry + rz * rz;
    const float d0 = r2 + 0.04f;
    const float denom = d0 * sqrtf(d0);          // (r2+eps)^1.5

    const float rdist = fmaxf(sqrtf(r2), 1e-6f);
    const float rinv  = 1.0f / rdist;
    float feat[7];
    feat[0] = px; feat[1] = py; feat[2] = pz;
    feat[3] = rx * rinv; feat[4] = ry * rinv; feat[5] = rz * rinv;
    feat[6] = rdist;

    float raw = b2[0];
    #pragma unroll
    for (int j = 0; j < HH; ++j) {
        float s = sb1[j];
        #pragma unroll
        for (int f = 0; f < 7; ++f) s += sW1[j * 7 + f] * feat[f];
        // exact GELU: 0.5*x*(1+erf(x/sqrt(2)))
        const float g = 0.5f * s * (1.0f + erff(s * 0.70710678118654752f));
        raw += sW2[j] * g;
    }
    const float corr = 1.0f + 0.5f * tanhf(raw);

    const float ddx = dd[bn * 3 + 0], ddy = dd[bn * 3 + 1], ddz = dd[bn * 3 + 2];
    const float dot = ddx * rx + ddy * ry + ddz * rz;

    A[idx] = amp[bn] * dot * corr / denom;
}

// Kernel 2: partial[c,b,k,t] = sum_{n in chunk c} A[b,n,k] * env[b,n,t]
__global__ __launch_bounds__(256) void reduce_kernel(
    const float* __restrict__ A,      // (B,N,K)
    const float* __restrict__ env,    // (B,N,T)
    float* __restrict__ partial)      // (NCHUNK,B,K,T)
{
    const int tid   = threadIdx.x;
    const int chunk = blockIdx.x;     // 0..NCHUNK-1
    const int ttile = blockIdx.y;     // 0..T/TTILE-1
    const int b     = blockIdx.z;
    const int t     = ttile * TTILE + tid;
    const int n0    = chunk * NPER;

    __shared__ float sA[NPER * KK];   // 32*9 = 288
    for (int i = tid; i < NPER * KK; i += 256)
        sA[i] = A[(b * NN + n0) * KK + i];
    __syncthreads();

    float acc[KK];
    #pragma unroll
    for (int k = 0; k < KK; ++k) acc[k] = 0.0f;

    const float* envp = env + ((size_t)(b * NN + n0)) * TT + t;
    #pragma unroll 4
    for (int nl = 0; nl < NPER; ++nl) {
        const float ev = envp[(size_t)nl * TT];
        #pragma unroll
        for (int k = 0; k < KK; ++k) acc[k] += sA[nl * KK + k] * ev;
    }

    float* pp = partial + (((size_t)chunk * BB + b) * KK) * TT + t;
    #pragma unroll
    for (int k = 0; k < KK; ++k) pp[(size_t)k * TT] = acc[k];
}

// Kernel 3: V = clip(sum_c partial, -50, 50); emit leads + V_electrodes
__global__ __launch_bounds__(256) void finalize_kernel(
    const float* __restrict__ partial,  // (NCHUNK,B,K,T)
    float* __restrict__ out)            // v_leads (B,12,T) then V_elec (B,K,T)
{
    const int idx = blockIdx.x * 256 + threadIdx.x;   // b*T + t, total 4096
    if (idx >= BB * TT) return;
    const int t = idx % TT;
    const int b = idx / TT;

    float V[KK];
    #pragma unroll
    for (int k = 0; k < KK; ++k) {
        float s = 0.0f;
        for (int c = 0; c < NCHUNK; ++c)
            s += partial[(((size_t)c * BB + b) * KK + k) * TT + t];
        V[k] = fminf(fmaxf(s, -50.0f), 50.0f);
    }

    float* vleads = out;                       // (B,12,T)
    float* velec  = out + (size_t)BB * 12 * TT; // (B,K,T)

    #pragma unroll
    for (int k = 0; k < KK; ++k)
        velec[((size_t)b * KK + k) * TT + t] = V[k];

    const float RA = V[0], LA = V[1], LL = V[2];
    const float WCT = (RA + LA + LL) * (1.0f / 3.0f);

    float L[12];
    L[0] = LA - RA;
    L[1] = LL - RA;
    L[2] = LL - LA;
    L[3] = RA - 0.5f * (LA + LL);
    L[4] = LA - 0.5f * (RA + LL);
    L[5] = LL - 0.5f * (RA + LA);
    L[6]  = V[3] - WCT;
    L[7]  = V[4] - WCT;
    L[8]  = V[5] - WCT;
    L[9]  = V[6] - WCT;
    L[10] = V[7] - WCT;
    L[11] = V[8] - WCT;

    #pragma unroll
    for (int l = 0; l < 12; ++l)
        vleads[((size_t)b * 12 + l) * TT + t] = L[l];
}

extern "C" void kernel_launch(void* const* d_in, const int* in_sizes, int n_in,
                              void* d_out, int out_size, void* d_ws, size_t ws_size,
                              hipStream_t stream) {
    const float* pos  = (const float*)d_in[0];
    const float* dd   = (const float*)d_in[1];
    const float* amp  = (const float*)d_in[2];
    const float* env  = (const float*)d_in[3];
    const float* eoff = (const float*)d_in[4];
    const float* W1   = (const float*)d_in[5];
    const float* b1   = (const float*)d_in[6];
    const float* W2   = (const float*)d_in[7];
    const float* b2   = (const float*)d_in[8];
    float* out = (float*)d_out;

    // Workspace layout
    float* A       = (float*)d_ws;                               // B*N*K floats = 294912 B
    float* partial = (float*)((char*)d_ws + (size_t)BB * NN * KK * sizeof(float)); // NCHUNK*B*K*T floats

    {
        const int total = BB * NN * KK;               // 73728
        coef_kernel<<<(total + 255) / 256, 256, 0, stream>>>(
            pos, dd, amp, eoff, W1, b1, W2, b2, A);
    }
    {
        dim3 grid(NCHUNK, TT / TTILE, BB);            // 32 x 2 x 8 = 512
        reduce_kernel<<<grid, 256, 0, stream>>>(A, env, partial);
    }
    {
        const int total = BB * TT;                    // 4096
        finalize_kernel<<<(total + 255) / 256, 256, 0, stream>>>(partial, out);
    }
}

// Round 2
// 34.499 us; speedup vs baseline: 1.2189x; 1.2189x over previous
//
#include <hip/hip_runtime.h>
#include <hip/hip_bf16.h>
#include <math.h>

// Problem constants
#define BB 8
#define NN 1024
#define TT 512
#define KK 9
#define HH 32

#define NCHUNK 32          // n-chunks in reduction
#define NPER   (NN/NCHUNK) // 32 n per chunk
#define TTILE  256         // t per block (2 ttiles)

__constant__ float c_epos[KK][3] = {
    { 0.30f,  0.25f, 0.00f},
    {-0.30f,  0.25f, 0.00f},
    {-0.05f, -0.40f, 0.00f},
    { 0.03f,  0.05f, 0.20f},
    { 0.00f,  0.05f, 0.22f},
    {-0.04f,  0.01f, 0.21f},
    {-0.08f, -0.02f, 0.18f},
    {-0.14f, -0.02f, 0.13f},
    {-0.20f, -0.02f, 0.07f},
};

// Fused kernel: per (chunk, ttile, b) block:
//   1. compute A[b, n0:n0+NPER, :] (amp * (dd.r) * corr / (r2+eps)^1.5) into LDS
//   2. partial[c,b,k,t] = sum_{n in chunk} A[n,k] * env[b,n,t]
__global__ __launch_bounds__(256) void fused_kernel(
    const float* __restrict__ pos,   // (B,N,3)
    const float* __restrict__ dd,    // (B,N,3)
    const float* __restrict__ amp,   // (B,N)
    const float* __restrict__ env,   // (B,N,T)
    const float* __restrict__ eoff,  // (B,K,3)
    const float* __restrict__ W1,    // (H,7)
    const float* __restrict__ b1,    // (H)
    const float* __restrict__ W2,    // (1,H)
    const float* __restrict__ b2,    // (1)
    float* __restrict__ partial)     // (NCHUNK,B,K,T)
{
    const int tid   = threadIdx.x;
    const int chunk = blockIdx.x;
    const int ttile = blockIdx.y;
    const int b     = blockIdx.z;
    const int n0    = chunk * NPER;
    const int t     = ttile * TTILE + tid;

    __shared__ float sW1[HH * 7];   // 224
    __shared__ float sb1[HH];
    __shared__ float sW2[HH];
    __shared__ float sb2;
    __shared__ float sE[KK][3];
    __shared__ float sA[NPER][12];  // 9 coeffs padded to 12 for float4 reads

    if (tid < HH * 7) sW1[tid] = W1[tid];
    if (tid < HH)     { sb1[tid] = b1[tid]; sW2[tid] = W2[tid]; }
    if (tid < KK * 3) sE[tid / 3][tid % 3] = c_epos[tid / 3][tid % 3] + eoff[b * KK * 3 + tid];
    if (tid == 255)   sb2 = b2[0];
    __syncthreads();

    // ---- coefficient phase: NPER*KK = 288 evals over 256 threads ----
    for (int idx = tid; idx < NPER * KK; idx += 256) {
        const int k  = idx % KK;
        const int nl = idx / KK;
        const int bn = b * NN + n0 + nl;

        const float px = pos[bn * 3 + 0];
        const float py = pos[bn * 3 + 1];
        const float pz = pos[bn * 3 + 2];

        const float rx = sE[k][0] - px, ry = sE[k][1] - py, rz = sE[k][2] - pz;
        const float r2 = rx * rx + ry * ry + rz * rz;
        const float d0 = r2 + 0.04f;
        const float denom = d0 * sqrtf(d0);

        const float rdist = fmaxf(sqrtf(r2), 1e-6f);
        const float rinv  = 1.0f / rdist;
        float feat[7];
        feat[0] = px; feat[1] = py; feat[2] = pz;
        feat[3] = rx * rinv; feat[4] = ry * rinv; feat[5] = rz * rinv;
        feat[6] = rdist;

        float raw = sb2;
        #pragma unroll
        for (int j = 0; j < HH; ++j) {
            float s = sb1[j];
            #pragma unroll
            for (int f = 0; f < 7; ++f) s += sW1[j * 7 + f] * feat[f];
            const float g = 0.5f * s * (1.0f + erff(s * 0.70710678118654752f));
            raw += sW2[j] * g;
        }
        const float corr = 1.0f + 0.5f * tanhf(raw);

        const float ddx = dd[bn * 3 + 0], ddy = dd[bn * 3 + 1], ddz = dd[bn * 3 + 2];
        const float dot = ddx * rx + ddy * ry + ddz * rz;

        sA[nl][k] = amp[bn] * dot * corr / denom;
    }
    __syncthreads();

    // ---- reduction phase: each thread owns one t ----
    float acc[KK];
    #pragma unroll
    for (int k = 0; k < KK; ++k) acc[k] = 0.0f;

    const float* envp = env + ((size_t)(b * NN + n0)) * TT + t;
    const float4* s4 = (const float4*)sA;
    #pragma unroll 8
    for (int nl = 0; nl < NPER; ++nl) {
        const float ev = envp[(size_t)nl * TT];
        const float4 a0 = s4[nl * 3 + 0];
        const float4 a1 = s4[nl * 3 + 1];
        const float  a8 = sA[nl][8];
        acc[0] += a0.x * ev; acc[1] += a0.y * ev; acc[2] += a0.z * ev;
        acc[3] += a0.w * ev; acc[4] += a1.x * ev; acc[5] += a1.y * ev;
        acc[6] += a1.z * ev; acc[7] += a1.w * ev; acc[8] += a8   * ev;
    }

    float* pp = partial + (((size_t)chunk * BB + b) * KK) * TT + t;
    #pragma unroll
    for (int k = 0; k < KK; ++k) pp[(size_t)k * TT] = acc[k];
}

// Finalize: V = clip(sum_c partial, -50, 50); emit leads + V_electrodes
// grid (TT/64, BB), 256 threads = 4 c-groups x 64 t
__global__ __launch_bounds__(256) void finalize_kernel(
    const float* __restrict__ partial,  // (NCHUNK,B,K,T)
    float* __restrict__ out)            // v_leads (B,12,T) then V_elec (B,K,T)
{
    const int tid = threadIdx.x;
    const int tl  = tid & 63;
    const int cg  = tid >> 6;       // 0..3
    const int tc  = blockIdx.x;     // 0..7
    const int b   = blockIdx.y;
    const int t   = tc * 64 + tl;

    float s[KK];
    #pragma unroll
    for (int k = 0; k < KK; ++k) s[k] = 0.0f;

    for (int c = cg; c < NCHUNK; c += 4) {
        const float* pp = partial + (((size_t)c * BB + b) * KK) * TT + t;
        #pragma unroll
        for (int k = 0; k < KK; ++k) s[k] += pp[(size_t)k * TT];
    }

    __shared__ float sV[4][KK][64];
    __shared__ float sR[KK][64];
    #pragma unroll
    for (int k = 0; k < KK; ++k) sV[cg][k][tl] = s[k];
    __syncthreads();

    for (int idx = tid; idx < KK * 64; idx += 256) {
        const int k   = idx >> 6;
        const int tl2 = idx & 63;
        float v = sV[0][k][tl2] + sV[1][k][tl2] + sV[2][k][tl2] + sV[3][k][tl2];
        sR[k][tl2] = fminf(fmaxf(v, -50.0f), 50.0f);
    }
    __syncthreads();

    if (tid < 64) {
        float V[KK];
        #pragma unroll
        for (int k = 0; k < KK; ++k) V[k] = sR[k][tid];

        float* vleads = out;                        // (B,12,T)
        float* velec  = out + (size_t)BB * 12 * TT; // (B,K,T)

        #pragma unroll
        for (int k = 0; k < KK; ++k)
            velec[((size_t)b * KK + k) * TT + t] = V[k];

        const float RA = V[0], LA = V[1], LL = V[2];
        const float WCT = (RA + LA + LL) * (1.0f / 3.0f);

        float L[12];
        L[0] = LA - RA;
        L[1] = LL - RA;
        L[2] = LL - LA;
        L[3] = RA - 0.5f * (LA + LL);
        L[4] = LA - 0.5f * (RA + LL);
        L[5] = LL - 0.5f * (RA + LA);
        L[6]  = V[3] - WCT;
        L[7]  = V[4] - WCT;
        L[8]  = V[5] - WCT;
        L[9]  = V[6] - WCT;
        L[10] = V[7] - WCT;
        L[11] = V[8] - WCT;

        #pragma unroll
        for (int l = 0; l < 12; ++l)
            vleads[((size_t)b * 12 + l) * TT + t] = L[l];
    }
}

extern "C" void kernel_launch(void* const* d_in, const int* in_sizes, int n_in,
                              void* d_out, int out_size, void* d_ws, size_t ws_size,
                              hipStream_t stream) {
    const float* pos  = (const float*)d_in[0];
    const float* dd   = (const float*)d_in[1];
    const float* amp  = (const float*)d_in[2];
    const float* env  = (const float*)d_in[3];
    const float* eoff = (const float*)d_in[4];
    const float* W1   = (const float*)d_in[5];
    const float* b1   = (const float*)d_in[6];
    const float* W2   = (const float*)d_in[7];
    const float* b2   = (const float*)d_in[8];
    float* out = (float*)d_out;

    float* partial = (float*)d_ws;   // (NCHUNK,B,K,T) floats = 4.7 MB

    {
        dim3 grid(NCHUNK, TT / TTILE, BB);   // 32 x 2 x 8 = 512 blocks
        fused_kernel<<<grid, 256, 0, stream>>>(
            pos, dd, amp, env, eoff, W1, b1, W2, b2, partial);
    }
    {
        dim3 grid(TT / 64, BB);              // 8 x 8 = 64 blocks
        finalize_kernel<<<grid, 256, 0, stream>>>(partial, out);
    }
}